// Round 4
// baseline (1262.607 us; speedup 1.0000x reference)
//
#include <hip/hip_runtime.h>
#include <hip/hip_bf16.h>
#include <math.h>

#define HW 16384      // 128*128
#define BATCH 4
#define KIDS 20

using short8 = __attribute__((ext_vector_type(8))) short;  // 8 bf16 = 16B
using f32x4  = __attribute__((ext_vector_type(4))) float;

__device__ __forceinline__ unsigned short bfbits(float f) {
  __hip_bfloat16 h = __float2bfloat16(f);
  return *(unsigned short*)&h;
}

__global__ __launch_bounds__(256) void zero_k(float* __restrict__ p, int n) {
  int i = blockIdx.x*256 + threadIdx.x;
  if (i < n) p[i] = 0.f;
}

// ---- x: fp32 NCHW [4][512][128][128] -> bf16 NHWC [4][16384][512] ----------
__global__ __launch_bounds__(256) void x_to_nhwc_k(const float* __restrict__ in,
                                                   __hip_bfloat16* __restrict__ out)
{
  __shared__ float tile[32][65];
  int t = blockIdx.x;
  const int pxt = t & 255; t >>= 8;
  const int ct  = t & 15;  t >>= 4;
  const int b   = t;
  const int tid = threadIdx.x;
  #pragma unroll
  for (int it = 0; it < 8; ++it) {
    int idx = tid + it*256;
    int px_l = idx & 63, c_l = idx >> 6;
    tile[c_l][px_l] = in[((size_t)(b*512 + ct*32 + c_l))*HW + pxt*64 + px_l];
  }
  __syncthreads();
  #pragma unroll
  for (int it = 0; it < 4; ++it) {
    int idx = tid + it*256;
    int c2 = idx & 15, px_l = idx >> 4;
    unsigned u = ((unsigned)bfbits(tile[c2*2+1][px_l]) << 16) | bfbits(tile[c2*2][px_l]);
    *(unsigned*)(out + ((size_t)(b*HW + pxt*64 + px_l))*512 + ct*32 + c2*2) = u;
  }
}

// ---- weights: fp32 [Co][Ci][3][3] -> bf16 [9][Co][Ci] ----------------------
template<int Co, int Ci>
__global__ __launch_bounds__(256) void pack_w_k(const float* __restrict__ w,
                                                __hip_bfloat16* __restrict__ out)
{
  const int i = blockIdx.x*256 + threadIdx.x;
  const int ci = i & (Ci-1);
  const int r  = i >> __builtin_ctz(Ci);
  const int co = r & (Co-1);
  const int t  = r >> __builtin_ctz(Co);
  out[i] = __float2bfloat16(w[((size_t)co*Ci + ci)*9 + t]);
}

// ---- implicit-GEMM conv3x3 via MFMA + fused GN partial stats ---------------
// block: ROWS output rows x 64 co, 4 waves (ROWS=2: wave = 1 row x 64 px;
// ROWS=1: wave = the row x 32 px).
// LDS q-split layout: plane (r*4+q) holds [130 px][8 ci] (16B per px slot).
//  - fragment ds_read_b128: 8-lane phases read 8 consecutive 16B slots ->
//    conflict-free.
//  - staging: wave-uniform (r,q16,pxgroup), lane i -> slot base + i*16B ->
//    exactly global_load_lds's required form (direct HBM/L2 -> LDS DMA).
template<int Ci, int Co, int ROWS, int CPG>
__global__ __launch_bounds__(256, 4) void conv_mfma_k(
    const __hip_bfloat16* __restrict__ xin,  // NHWC bf16 [4][16384][Ci]
    const __hip_bfloat16* __restrict__ wpk,  // [9][Co][Ci] bf16
    const float* __restrict__ bias,
    float* __restrict__ out,                 // NHWC fp32 [4][16384][Co]
    float* __restrict__ partS, float* __restrict__ partSS)
{
  constexpr int NW = 4 / ROWS;         // waves along px
  constexpr int WN = 128 / NW;         // px per wave
  constexpr int NT = WN / 16;
  constexpr int MT = 4;                // 64 co per block
  constexpr int SR = ROWS + 2;
  constexpr int RG = 128 / ROWS;
  constexpr int NG = 64 / CPG;
  __shared__ __align__(16) short bl[SR*4*130*8];

  const int b  = blockIdx.x / RG;
  const int r0 = (blockIdx.x % RG) * ROWS;
  const int co0 = blockIdx.y * 64;
  const int tid = threadIdx.x;
  const int wave = tid >> 6, lane = tid & 63;
  const int row_w = wave % ROWS;
  const int wn    = wave / ROWS;
  const int y = r0 + row_w;
  const int lr = lane & 15, q = lane >> 4;

  // zero px-pad slots (slot 0 and 129 of each (r,q) plane) once
  if (tid < SR*4*2) {
    int side = tid & 1, rq = tid >> 1;
    short8 z = {0,0,0,0,0,0,0,0};
    *(short8*)(bl + (rq*130 + (side ? 129 : 0))*8) = z;
  }

  f32x4 acc[MT][NT] = {};
  const size_t in_base = (size_t)b * HW * Ci;

  for (int ci0 = 0; ci0 < Ci; ci0 += 32) {
    __syncthreads();
    // stage SR rows x 128 px x 32 ci: SR*4*2 wave-issues of 64x16B
    #pragma unroll
    for (int it = 0; it < SR*2; ++it) {
      const int iid = it*4 + wave;            // < SR*8
      const int r = iid >> 3, q16 = (iid >> 1) & 3, pxg = iid & 1;
      const int yy = r0 + r - 1;
      short* lp = bl + ((r*4 + q16)*130 + pxg*64 + 1)*8;
      if ((unsigned)yy < 128u) {
        const __hip_bfloat16* gp = xin + in_base +
            (size_t)(yy*128 + pxg*64 + lane)*Ci + ci0 + q16*8;
        __builtin_amdgcn_global_load_lds(
            (const __attribute__((address_space(1))) void*)gp,
            (__attribute__((address_space(3))) void*)lp, 16, 0, 0);
      } else {
        short8 z = {0,0,0,0,0,0,0,0};
        *(short8*)(lp + lane*8) = z;
      }
    }
    __syncthreads();
    #pragma unroll
    for (int t = 0; t < 9; ++t) {
      const int dy = t / 3, dx = t % 3;
      short8 af[MT], bf[NT];
      #pragma unroll
      for (int mt = 0; mt < MT; ++mt)
        af[mt] = *(const short8*)(wpk +
            ((size_t)(t*Co + co0 + mt*16 + lr))*Ci + ci0 + q*8);
      #pragma unroll
      for (int nt = 0; nt < NT; ++nt)
        bf[nt] = *(const short8*)(bl +
            (((row_w + dy)*4 + q)*130 + wn*WN + nt*16 + lr + dx)*8);
      #pragma unroll
      for (int mt = 0; mt < MT; ++mt)
        #pragma unroll
        for (int nt = 0; nt < NT; ++nt)
          acc[mt][nt] = __builtin_amdgcn_mfma_f32_16x16x32_bf16(
              af[mt], bf[nt], acc[mt][nt], 0, 0, 0);
    }
  }

  // epilogue: +bias, store, fused GN partial stats
  float sg[NG] = {}, ssg[NG] = {};
  #pragma unroll
  for (int mt = 0; mt < MT; ++mt) {
    const int g = (mt*16) / CPG;
    #pragma unroll
    for (int nt = 0; nt < NT; ++nt) {
      int px = wn*WN + nt*16 + lr;
      int co = co0 + mt*16 + q*4;
      const float4 bv = *(const float4*)(bias + co);
      f32x4 v = acc[mt][nt];
      v[0] += bv.x; v[1] += bv.y; v[2] += bv.z; v[3] += bv.w;
      sg[g]  += v[0] + v[1] + v[2] + v[3];
      ssg[g] += v[0]*v[0] + v[1]*v[1] + v[2]*v[2] + v[3]*v[3];
      *(f32x4*)(out + ((size_t)(b*HW + y*128 + px))*Co + co) = v;
    }
  }
  const int bgbase = b*(Co/CPG) + co0/CPG;
  #pragma unroll
  for (int g = 0; g < NG; ++g) {
    float s = sg[g], ss = ssg[g];
    #pragma unroll
    for (int off = 32; off; off >>= 1) {
      s  += __shfl_xor(s, off);
      ss += __shfl_xor(ss, off);
    }
    if (lane == 0) {
      atomicAdd(&partS[bgbase + g], s);
      atomicAdd(&partSS[bgbase + g], ss);
    }
  }
}

// ---- GN finalize -----------------------------------------------------------
__global__ void gn_final_k(const float* __restrict__ partS,
                           const float* __restrict__ partSS,
                           float* __restrict__ mv, int nbg, float inv_n)
{
  const int i = threadIdx.x;
  if (i < nbg) {
    float s = partS[i], ss = partSS[i];
    float mean = s*inv_n, var = ss*inv_n - mean*mean;
    mv[2*i] = mean; mv[2*i+1] = rsqrtf(var + 1e-5f);
  }
}

// ---- GN apply: normalize+affine+ReLU; emit bf16 (or fp32) NHWC -------------
template<int C, int CPG, bool BF16OUT>
__global__ __launch_bounds__(256) void gn_apply_k(const float* __restrict__ in,
    const float* __restrict__ mv, const float* __restrict__ gw,
    const float* __restrict__ gb, void* __restrict__ outp)
{
  constexpr int C4 = C/4;
  constexpr int G = C/CPG;
  const int i = blockIdx.x*256 + threadIdx.x;
  const int c4 = i & (C4-1);
  const int pxb = i >> __builtin_ctz(C4);
  const int b = pxb >> 14;
  const int c = c4*4;
  const int bg = b*G + c/CPG;
  const float mean = mv[2*bg], inv = mv[2*bg+1];
  float4 v = *((const float4*)in + i);
  const float4 w4 = *(const float4*)(gw + c);
  const float4 b4 = *(const float4*)(gb + c);
  float r0 = fmaxf((v.x-mean)*inv*w4.x + b4.x, 0.f);
  float r1 = fmaxf((v.y-mean)*inv*w4.y + b4.y, 0.f);
  float r2 = fmaxf((v.z-mean)*inv*w4.z + b4.z, 0.f);
  float r3 = fmaxf((v.w-mean)*inv*w4.w + b4.w, 0.f);
  if (BF16OUT) {
    uint2 o;
    o.x = ((unsigned)bfbits(r1) << 16) | bfbits(r0);
    o.y = ((unsigned)bfbits(r3) << 16) | bfbits(r2);
    *(uint2*)((__hip_bfloat16*)outp + (size_t)i*4) = o;
  } else {
    *((float4*)outp + i) = make_float4(r0,r1,r2,r3);
  }
}

// ---- pooling ---------------------------------------------------------------
__global__ __launch_bounds__(256) void pool_counts_k(
    const int* __restrict__ masks, float* __restrict__ counts)
{
  __shared__ int hist[KIDS];
  const int b = blockIdx.x;
  if (threadIdx.x < KIDS) hist[threadIdx.x] = 0;
  __syncthreads();
  for (int p = threadIdx.x; p < HW; p += 256) {
    const int m = masks[b*HW + p];
    if (m > 0) atomicAdd(&hist[m-1], 1);
  }
  __syncthreads();
  if (threadIdx.x < KIDS) counts[b*KIDS + threadIdx.x] = (float)hist[threadIdx.x];
}

__global__ __launch_bounds__(256) void pool_sums_k(const float* __restrict__ h3,
    const int* __restrict__ masks, float* __restrict__ sums)
{
  __shared__ float acc[KIDS*64];
  const int b = blockIdx.x >> 5, chunk = blockIdx.x & 31;
  const int tid = threadIdx.x;
  for (int j = tid; j < KIDS*64; j += 256) acc[j] = 0.f;
  __syncthreads();
  const int ch = tid & 63, pi = tid >> 6;
  const int p0 = chunk*512;
  for (int p = p0 + pi; p < p0 + 512; p += 4) {
    int m = masks[b*HW + p];
    if (m > 0) atomicAdd(&acc[(m-1)*64 + ch], h3[((size_t)(b*HW + p))*64 + ch]);
  }
  __syncthreads();
  for (int j = tid; j < KIDS*64; j += 256) atomicAdd(&sums[b*KIDS*64 + j], acc[j]);
}

// ---- heads: one wave per (b,k) ---------------------------------------------
__global__ __launch_bounds__(64) void heads_k(
    const float* __restrict__ sums, const float* __restrict__ counts,
    const float* __restrict__ wb, const float* __restrict__ bb,
    const float* __restrict__ wc, const float* __restrict__ bc,
    float* __restrict__ out)
{
  const int bk = blockIdx.x;
  const int c = threadIdx.x;
  const float pooled = sums[bk*64 + c] / (counts[bk] + 1e-6f);
  #pragma unroll
  for (int o = 0; o < 7; ++o) {
    float t = pooled * wb[o*64 + c];
    for (int off = 32; off > 0; off >>= 1) t += __shfl_down(t, off);
    if (c == 0) out[bk*7 + o] = t + bb[o];
  }
  float t = pooled * wc[c];
  for (int off = 32; off > 0; off >>= 1) t += __shfl_down(t, off);
  if (c == 0) out[BATCH*KIDS*7 + bk] = 1.f / (1.f + expf(-(t + bc[0])));
}

extern "C" void kernel_launch(void* const* d_in, const int* in_sizes, int n_in,
                              void* d_out, int out_size, void* d_ws, size_t ws_size,
                              hipStream_t stream)
{
  const float* x     = (const float*)d_in[0];
  const int*   masks = (const int*)  d_in[1];
  const float* w1 = (const float*)d_in[2];
  const float* b1 = (const float*)d_in[3];
  const float* g1w= (const float*)d_in[4];
  const float* g1b= (const float*)d_in[5];
  const float* w2 = (const float*)d_in[6];
  const float* b2 = (const float*)d_in[7];
  const float* g2w= (const float*)d_in[8];
  const float* g2b= (const float*)d_in[9];
  const float* w3 = (const float*)d_in[10];
  const float* b3 = (const float*)d_in[11];
  const float* g3w= (const float*)d_in[12];
  const float* g3b= (const float*)d_in[13];
  const float* wb = (const float*)d_in[14];
  const float* bb = (const float*)d_in[15];
  const float* wc = (const float*)d_in[16];
  const float* bc = (const float*)d_in[17];
  float* out = (float*)d_out;

  char* ws = (char*)d_ws;
  // region A [0,64MB): xb during conv1; then h1b(32) + h2b(16) + h3(16)
  __hip_bfloat16* xb  = (__hip_bfloat16*)ws;
  __hip_bfloat16* h1b = (__hip_bfloat16*)ws;
  __hip_bfloat16* h2b = (__hip_bfloat16*)(ws + (size_t)(32<<20));
  float*          h3  = (float*)         (ws + (size_t)(48<<20));
  // region B [64,128MB): c1(64); then c2(32)+c3(16)
  float* c1 = (float*)(ws + (size_t)(64<<20));
  float* c2 = c1;
  float* c3 = (float*)(ws + (size_t)(96<<20));
  // packed weights + small buffers at 128MB
  __hip_bfloat16* wp1 = (__hip_bfloat16*)(ws + (size_t)(128<<20));
  __hip_bfloat16* wp2 = wp1 + 9*256*512;
  __hip_bfloat16* wp3 = wp2 + 9*128*256;
  char* tail = (char*)(wp3 + 9*64*128);
  float* mv     = (float*)tail;                 // 64
  float* partS  = mv + 64;                      // 64 (layer offs 0/32/48)
  float* partSS = partS + 64;                   // 64
  float* sums   = partSS + 64;                  // 5120
  float* counts = sums + 5120;                  // 80

  zero_k<<<21, 256, 0, stream>>>(partS, 64 + 64 + 5120);

  x_to_nhwc_k<<<16384, 256, 0, stream>>>(x, xb);
  pack_w_k<256,512><<<4608, 256, 0, stream>>>(w1, wp1);
  pack_w_k<128,256><<<1152, 256, 0, stream>>>(w2, wp2);
  pack_w_k< 64,128><<< 288, 256, 0, stream>>>(w3, wp3);

  // layer 1: 512 -> 256, GN(8 groups, cpg 32)
  conv_mfma_k<512,256,2,32><<<dim3(256,4), 256, 0, stream>>>(
      xb, wp1, b1, c1, partS, partSS);
  gn_final_k<<<1, 64, 0, stream>>>(partS, partSS, mv, 32, 1.f/(32.f*HW));
  gn_apply_k<256,32,true><<<16384, 256, 0, stream>>>(c1, mv, g1w, g1b, h1b);

  // layer 2: 256 -> 128, GN(4 groups, cpg 32)
  conv_mfma_k<256,128,2,32><<<dim3(256,2), 256, 0, stream>>>(
      h1b, wp2, b2, c2, partS + 32, partSS + 32);
  gn_final_k<<<1, 64, 0, stream>>>(partS + 32, partSS + 32, mv, 16, 1.f/(32.f*HW));
  gn_apply_k<128,32,true><<<8192, 256, 0, stream>>>(c2, mv, g2w, g2b, h2b);

  // layer 3: 128 -> 64, GN(4 groups, cpg 16); fp32 out for pooling
  conv_mfma_k<128,64,1,16><<<dim3(512,1), 256, 0, stream>>>(
      h2b, wp3, b3, c3, partS + 48, partSS + 48);
  gn_final_k<<<1, 64, 0, stream>>>(partS + 48, partSS + 48, mv, 16, 1.f/(16.f*HW));
  gn_apply_k<64,16,false><<<4096, 256, 0, stream>>>(c3, mv, g3w, g3b, h3);

  // pooling + heads
  pool_counts_k<<<BATCH, 256, 0, stream>>>(masks, counts);
  pool_sums_k<<<BATCH*32, 256, 0, stream>>>(h3, masks, sums);
  heads_k<<<BATCH*KIDS, 64, 0, stream>>>(sums, counts, wb, bb, wc, bc, out);
}

// Round 5
// 1033.117 us; speedup vs baseline: 1.2221x; 1.2221x over previous
//
#include <hip/hip_runtime.h>
#include <hip/hip_bf16.h>
#include <math.h>

#define HW 16384      // 128*128
#define BATCH 4
#define KIDS 20

using short8 = __attribute__((ext_vector_type(8))) short;  // 8 bf16 = 16B
using f32x4  = __attribute__((ext_vector_type(4))) float;

__device__ __forceinline__ unsigned short bfbits(float f) {
  __hip_bfloat16 h = __float2bfloat16(f);
  return *(unsigned short*)&h;
}

__global__ __launch_bounds__(256) void zero_k(float* __restrict__ p, int n) {
  int i = blockIdx.x*256 + threadIdx.x;
  if (i < n) p[i] = 0.f;
}

// ---- x: fp32 NCHW [4][512][128][128] -> bf16 NHWC [4][16384][512] ----------
__global__ __launch_bounds__(256) void x_to_nhwc_k(const float* __restrict__ in,
                                                   __hip_bfloat16* __restrict__ out)
{
  __shared__ float tile[32][65];
  int t = blockIdx.x;
  const int pxt = t & 255; t >>= 8;
  const int ct  = t & 15;  t >>= 4;
  const int b   = t;
  const int tid = threadIdx.x;
  #pragma unroll
  for (int it = 0; it < 8; ++it) {
    int idx = tid + it*256;
    int px_l = idx & 63, c_l = idx >> 6;
    tile[c_l][px_l] = in[((size_t)(b*512 + ct*32 + c_l))*HW + pxt*64 + px_l];
  }
  __syncthreads();
  #pragma unroll
  for (int it = 0; it < 4; ++it) {
    int idx = tid + it*256;
    int c2 = idx & 15, px_l = idx >> 4;
    unsigned u = ((unsigned)bfbits(tile[c2*2+1][px_l]) << 16) | bfbits(tile[c2*2][px_l]);
    *(unsigned*)(out + ((size_t)(b*HW + pxt*64 + px_l))*512 + ct*32 + c2*2) = u;
  }
}

// ---- weights: fp32 [Co][Ci][3][3] -> bf16 [9][Co][Ci] ----------------------
template<int Co, int Ci>
__global__ __launch_bounds__(256) void pack_w_k(const float* __restrict__ w,
                                                __hip_bfloat16* __restrict__ out)
{
  const int i = blockIdx.x*256 + threadIdx.x;
  const int ci = i & (Ci-1);
  const int r  = i >> __builtin_ctz(Ci);
  const int co = r & (Co-1);
  const int t  = r >> __builtin_ctz(Co);
  out[i] = __float2bfloat16(w[((size_t)co*Ci + ci)*9 + t]);
}

// ---- implicit-GEMM conv3x3 via MFMA, double-buffered LDS pipeline ----------
// block: ROWS output rows x 64 co, 4 waves. LDS: 2 x [SR rows][128 px][32 ci]
// (no pad slots; boundary B-frags masked to zero). Stage chunk c+1 issued
// post-barrier, overlapped with compute of chunk c; ONE barrier per chunk.
template<int Ci, int Co, int ROWS, int CPG>
__global__ __launch_bounds__(256, 2) void conv_mfma_k(
    const __hip_bfloat16* __restrict__ xin,  // NHWC bf16 [4][16384][Ci]
    const __hip_bfloat16* __restrict__ wpk,  // [9][Co][Ci] bf16
    const float* __restrict__ bias,
    float* __restrict__ out,                 // NHWC fp32 [4][16384][Co]
    float* __restrict__ partS, float* __restrict__ partSS)
{
  constexpr int NW = 4 / ROWS;         // waves along px
  constexpr int WN = 128 / NW;         // px per wave
  constexpr int NT = WN / 16;
  constexpr int MT = 4;                // 64 co per block
  constexpr int SR = ROWS + 2;
  constexpr int RG = 128 / ROWS;
  constexpr int NG = 64 / CPG;
  constexpr int NC = Ci / 32;
  constexpr int BSZ = SR*128*32;       // shorts per buffer (32 KB)
  __shared__ __align__(16) short bl[2*BSZ];

  const int b  = blockIdx.x / RG;
  const int r0 = (blockIdx.x % RG) * ROWS;
  const int co0 = blockIdx.y * 64;
  const int tid = threadIdx.x;
  const int wave = tid >> 6, lane = tid & 63;
  const int row_w = wave % ROWS;
  const int wn    = wave / ROWS;
  const int y = r0 + row_w;
  const int lr = lane & 15, q = lane >> 4;
  const size_t in_base = (size_t)b * HW * Ci;

  // coalesced staging: 4 consecutive threads cover one px's 64B (full lines)
  auto stage = [&](int bufi, int ci0) {
    #pragma unroll
    for (int it = 0; it < 2*SR; ++it) {
      int idx = tid + it*256;
      int q16 = idx & 3, px = (idx >> 2) & 127, r = idx >> 9;
      int yy = r0 + r - 1;
      short8 v = {0,0,0,0,0,0,0,0};
      if ((unsigned)yy < 128u)
        v = *(const short8*)(xin + in_base + (size_t)(yy*128 + px)*Ci + ci0 + q16*8);
      *(short8*)(bl + bufi*BSZ + ((r*128 + px)*32) + q16*8) = v;
    }
  };

  f32x4 acc[MT][NT] = {};

  stage(0, 0);
  __syncthreads();

  for (int c = 0; c < NC; ++c) {
    const int cur = c & 1;
    if (c + 1 < NC) stage(cur ^ 1, (c+1)*32);   // overlaps with compute below
    const int ci0 = c*32;
    #pragma unroll
    for (int t = 0; t < 9; ++t) {
      const int dy = t / 3, dx = t % 3;
      short8 af[MT], bf[NT];
      #pragma unroll
      for (int mt = 0; mt < MT; ++mt)
        af[mt] = *(const short8*)(wpk +
            ((size_t)(t*Co + co0 + mt*16 + lr))*Ci + ci0 + q*8);
      #pragma unroll
      for (int nt = 0; nt < NT; ++nt) {
        int slot = wn*WN + nt*16 + lr + dx - 1;   // px in [-1,128]
        if (nt == 0 || nt == NT-1) {
          int sc = slot & 127;
          short8 v = *(const short8*)(bl + cur*BSZ +
              (((row_w + dy)*128 + sc)*32) + q*8);
          if ((unsigned)slot >= 128u) v = (short8){0,0,0,0,0,0,0,0};
          bf[nt] = v;
        } else {
          bf[nt] = *(const short8*)(bl + cur*BSZ +
              (((row_w + dy)*128 + slot)*32) + q*8);
        }
      }
      #pragma unroll
      for (int mt = 0; mt < MT; ++mt)
        #pragma unroll
        for (int nt = 0; nt < NT; ++nt)
          acc[mt][nt] = __builtin_amdgcn_mfma_f32_16x16x32_bf16(
              af[mt], bf[nt], acc[mt][nt], 0, 0, 0);
    }
    __syncthreads();   // staged c+1 complete; reads of cur complete
  }

  // epilogue: +bias, store, fused GN partial stats
  float sg[NG] = {}, ssg[NG] = {};
  #pragma unroll
  for (int mt = 0; mt < MT; ++mt) {
    const int g = (mt*16) / CPG;
    #pragma unroll
    for (int nt = 0; nt < NT; ++nt) {
      int px = wn*WN + nt*16 + lr;
      int co = co0 + mt*16 + q*4;
      const float4 bv = *(const float4*)(bias + co);
      f32x4 v = acc[mt][nt];
      v[0] += bv.x; v[1] += bv.y; v[2] += bv.z; v[3] += bv.w;
      sg[g]  += v[0] + v[1] + v[2] + v[3];
      ssg[g] += v[0]*v[0] + v[1]*v[1] + v[2]*v[2] + v[3]*v[3];
      *(f32x4*)(out + ((size_t)(b*HW + y*128 + px))*Co + co) = v;
    }
  }
  const int bgbase = b*(Co/CPG) + co0/CPG;
  #pragma unroll
  for (int g = 0; g < NG; ++g) {
    float s = sg[g], ss = ssg[g];
    #pragma unroll
    for (int off = 32; off; off >>= 1) {
      s  += __shfl_xor(s, off);
      ss += __shfl_xor(ss, off);
    }
    if (lane == 0) {
      atomicAdd(&partS[bgbase + g], s);
      atomicAdd(&partSS[bgbase + g], ss);
    }
  }
}

// ---- GN finalize -----------------------------------------------------------
__global__ void gn_final_k(const float* __restrict__ partS,
                           const float* __restrict__ partSS,
                           float* __restrict__ mv, int nbg, float inv_n)
{
  const int i = threadIdx.x;
  if (i < nbg) {
    float s = partS[i], ss = partSS[i];
    float mean = s*inv_n, var = ss*inv_n - mean*mean;
    mv[2*i] = mean; mv[2*i+1] = rsqrtf(var + 1e-5f);
  }
}

// ---- GN apply: normalize+affine+ReLU; emit bf16 (or fp32) NHWC -------------
template<int C, int CPG, bool BF16OUT>
__global__ __launch_bounds__(256) void gn_apply_k(const float* __restrict__ in,
    const float* __restrict__ mv, const float* __restrict__ gw,
    const float* __restrict__ gb, void* __restrict__ outp)
{
  constexpr int C4 = C/4;
  constexpr int G = C/CPG;
  const int i = blockIdx.x*256 + threadIdx.x;
  const int c4 = i & (C4-1);
  const int pxb = i >> __builtin_ctz(C4);
  const int b = pxb >> 14;
  const int c = c4*4;
  const int bg = b*G + c/CPG;
  const float mean = mv[2*bg], inv = mv[2*bg+1];
  float4 v = *((const float4*)in + i);
  const float4 w4 = *(const float4*)(gw + c);
  const float4 b4 = *(const float4*)(gb + c);
  float r0 = fmaxf((v.x-mean)*inv*w4.x + b4.x, 0.f);
  float r1 = fmaxf((v.y-mean)*inv*w4.y + b4.y, 0.f);
  float r2 = fmaxf((v.z-mean)*inv*w4.z + b4.z, 0.f);
  float r3 = fmaxf((v.w-mean)*inv*w4.w + b4.w, 0.f);
  if (BF16OUT) {
    uint2 o;
    o.x = ((unsigned)bfbits(r1) << 16) | bfbits(r0);
    o.y = ((unsigned)bfbits(r3) << 16) | bfbits(r2);
    *(uint2*)((__hip_bfloat16*)outp + (size_t)i*4) = o;
  } else {
    *((float4*)outp + i) = make_float4(r0,r1,r2,r3);
  }
}

// ---- pooling ---------------------------------------------------------------
__global__ __launch_bounds__(256) void pool_counts_k(
    const int* __restrict__ masks, float* __restrict__ counts)
{
  __shared__ int hist[KIDS];
  const int b = blockIdx.x;
  if (threadIdx.x < KIDS) hist[threadIdx.x] = 0;
  __syncthreads();
  for (int p = threadIdx.x; p < HW; p += 256) {
    const int m = masks[b*HW + p];
    if (m > 0) atomicAdd(&hist[m-1], 1);
  }
  __syncthreads();
  if (threadIdx.x < KIDS) counts[b*KIDS + threadIdx.x] = (float)hist[threadIdx.x];
}

__global__ __launch_bounds__(256) void pool_sums_k(const float* __restrict__ h3,
    const int* __restrict__ masks, float* __restrict__ sums)
{
  __shared__ float acc[KIDS*64];
  const int b = blockIdx.x >> 5, chunk = blockIdx.x & 31;
  const int tid = threadIdx.x;
  for (int j = tid; j < KIDS*64; j += 256) acc[j] = 0.f;
  __syncthreads();
  const int ch = tid & 63, pi = tid >> 6;
  const int p0 = chunk*512;
  for (int p = p0 + pi; p < p0 + 512; p += 4) {
    int m = masks[b*HW + p];
    if (m > 0) atomicAdd(&acc[(m-1)*64 + ch], h3[((size_t)(b*HW + p))*64 + ch]);
  }
  __syncthreads();
  for (int j = tid; j < KIDS*64; j += 256) atomicAdd(&sums[b*KIDS*64 + j], acc[j]);
}

// ---- heads: one wave per (b,k) ---------------------------------------------
__global__ __launch_bounds__(64) void heads_k(
    const float* __restrict__ sums, const float* __restrict__ counts,
    const float* __restrict__ wb, const float* __restrict__ bb,
    const float* __restrict__ wc, const float* __restrict__ bc,
    float* __restrict__ out)
{
  const int bk = blockIdx.x;
  const int c = threadIdx.x;
  const float pooled = sums[bk*64 + c] / (counts[bk] + 1e-6f);
  #pragma unroll
  for (int o = 0; o < 7; ++o) {
    float t = pooled * wb[o*64 + c];
    for (int off = 32; off > 0; off >>= 1) t += __shfl_down(t, off);
    if (c == 0) out[bk*7 + o] = t + bb[o];
  }
  float t = pooled * wc[c];
  for (int off = 32; off > 0; off >>= 1) t += __shfl_down(t, off);
  if (c == 0) out[BATCH*KIDS*7 + bk] = 1.f / (1.f + expf(-(t + bc[0])));
}

extern "C" void kernel_launch(void* const* d_in, const int* in_sizes, int n_in,
                              void* d_out, int out_size, void* d_ws, size_t ws_size,
                              hipStream_t stream)
{
  const float* x     = (const float*)d_in[0];
  const int*   masks = (const int*)  d_in[1];
  const float* w1 = (const float*)d_in[2];
  const float* b1 = (const float*)d_in[3];
  const float* g1w= (const float*)d_in[4];
  const float* g1b= (const float*)d_in[5];
  const float* w2 = (const float*)d_in[6];
  const float* b2 = (const float*)d_in[7];
  const float* g2w= (const float*)d_in[8];
  const float* g2b= (const float*)d_in[9];
  const float* w3 = (const float*)d_in[10];
  const float* b3 = (const float*)d_in[11];
  const float* g3w= (const float*)d_in[12];
  const float* g3b= (const float*)d_in[13];
  const float* wb = (const float*)d_in[14];
  const float* bb = (const float*)d_in[15];
  const float* wc = (const float*)d_in[16];
  const float* bc = (const float*)d_in[17];
  float* out = (float*)d_out;

  char* ws = (char*)d_ws;
  // region A [0,64MB): xb during conv1; then h1b(32) + h2b(16) + h3(16)
  __hip_bfloat16* xb  = (__hip_bfloat16*)ws;
  __hip_bfloat16* h1b = (__hip_bfloat16*)ws;
  __hip_bfloat16* h2b = (__hip_bfloat16*)(ws + (size_t)(32<<20));
  float*          h3  = (float*)         (ws + (size_t)(48<<20));
  // region B [64,128MB): c1(64); then c2(32)+c3(16)
  float* c1 = (float*)(ws + (size_t)(64<<20));
  float* c2 = c1;
  float* c3 = (float*)(ws + (size_t)(96<<20));
  // packed weights + small buffers at 128MB
  __hip_bfloat16* wp1 = (__hip_bfloat16*)(ws + (size_t)(128<<20));
  __hip_bfloat16* wp2 = wp1 + 9*256*512;
  __hip_bfloat16* wp3 = wp2 + 9*128*256;
  char* tail = (char*)(wp3 + 9*64*128);
  float* mv     = (float*)tail;                 // 64
  float* partS  = mv + 64;                      // 64 (layer offs 0/32/48)
  float* partSS = partS + 64;                   // 64
  float* sums   = partSS + 64;                  // 5120
  float* counts = sums + 5120;                  // 80

  zero_k<<<21, 256, 0, stream>>>(partS, 64 + 64 + 5120);

  x_to_nhwc_k<<<16384, 256, 0, stream>>>(x, xb);
  pack_w_k<256,512><<<4608, 256, 0, stream>>>(w1, wp1);
  pack_w_k<128,256><<<1152, 256, 0, stream>>>(w2, wp2);
  pack_w_k< 64,128><<< 288, 256, 0, stream>>>(w3, wp3);

  // layer 1: 512 -> 256, GN(8 groups, cpg 32)
  conv_mfma_k<512,256,2,32><<<dim3(256,4), 256, 0, stream>>>(
      xb, wp1, b1, c1, partS, partSS);
  gn_final_k<<<1, 64, 0, stream>>>(partS, partSS, mv, 32, 1.f/(32.f*HW));
  gn_apply_k<256,32,true><<<16384, 256, 0, stream>>>(c1, mv, g1w, g1b, h1b);

  // layer 2: 256 -> 128, GN(4 groups, cpg 32)
  conv_mfma_k<256,128,2,32><<<dim3(256,2), 256, 0, stream>>>(
      h1b, wp2, b2, c2, partS + 32, partSS + 32);
  gn_final_k<<<1, 64, 0, stream>>>(partS + 32, partSS + 32, mv, 16, 1.f/(32.f*HW));
  gn_apply_k<128,32,true><<<8192, 256, 0, stream>>>(c2, mv, g2w, g2b, h2b);

  // layer 3: 128 -> 64, GN(4 groups, cpg 16); fp32 out for pooling
  conv_mfma_k<128,64,1,16><<<dim3(512,1), 256, 0, stream>>>(
      h2b, wp3, b3, c3, partS + 48, partSS + 48);
  gn_final_k<<<1, 64, 0, stream>>>(partS + 48, partSS + 48, mv, 16, 1.f/(16.f*HW));
  gn_apply_k<64,16,false><<<4096, 256, 0, stream>>>(c3, mv, g3w, g3b, h3);

  // pooling + heads
  pool_counts_k<<<BATCH, 256, 0, stream>>>(masks, counts);
  pool_sums_k<<<BATCH*32, 256, 0, stream>>>(h3, masks, sums);
  heads_k<<<BATCH*KIDS, 64, 0, stream>>>(sums, counts, wb, bb, wc, bc, out);
}

// Round 6
// 981.062 us; speedup vs baseline: 1.2870x; 1.0531x over previous
//
#include <hip/hip_runtime.h>
#include <hip/hip_bf16.h>
#include <math.h>

#define HW 16384      // 128*128
#define BATCH 4
#define KIDS 20

using short8 = __attribute__((ext_vector_type(8))) short;  // 8 bf16 = 16B
using f32x4  = __attribute__((ext_vector_type(4))) float;

__device__ __forceinline__ unsigned short bfbits(float f) {
  __hip_bfloat16 h = __float2bfloat16(f);
  return *(unsigned short*)&h;
}

__global__ __launch_bounds__(256) void zero_k(float* __restrict__ p, int n) {
  int i = blockIdx.x*256 + threadIdx.x;
  if (i < n) p[i] = 0.f;
}

// ---- x: fp32 NCHW [4][512][128][128] -> bf16 NHWC [4][16384][512] ----------
__global__ __launch_bounds__(256) void x_to_nhwc_k(const float* __restrict__ in,
                                                   __hip_bfloat16* __restrict__ out)
{
  __shared__ float tile[32][65];
  int t = blockIdx.x;
  const int pxt = t & 255; t >>= 8;
  const int ct  = t & 15;  t >>= 4;
  const int b   = t;
  const int tid = threadIdx.x;
  #pragma unroll
  for (int it = 0; it < 8; ++it) {
    int idx = tid + it*256;
    int px_l = idx & 63, c_l = idx >> 6;
    tile[c_l][px_l] = in[((size_t)(b*512 + ct*32 + c_l))*HW + pxt*64 + px_l];
  }
  __syncthreads();
  #pragma unroll
  for (int it = 0; it < 4; ++it) {
    int idx = tid + it*256;
    int c2 = idx & 15, px_l = idx >> 4;
    unsigned u = ((unsigned)bfbits(tile[c2*2+1][px_l]) << 16) | bfbits(tile[c2*2][px_l]);
    *(unsigned*)(out + ((size_t)(b*HW + pxt*64 + px_l))*512 + ct*32 + c2*2) = u;
  }
}

// ---- weights: fp32 [Co][Ci][3][3] -> bf16 [9][Co][Ci] ----------------------
template<int Co, int Ci>
__global__ __launch_bounds__(256) void pack_w_k(const float* __restrict__ w,
                                                __hip_bfloat16* __restrict__ out)
{
  const int i = blockIdx.x*256 + threadIdx.x;
  const int ci = i & (Ci-1);
  const int r  = i >> __builtin_ctz(Ci);
  const int co = r & (Co-1);
  const int t  = r >> __builtin_ctz(Co);
  out[i] = __float2bfloat16(w[((size_t)co*Ci + ci)*9 + t]);
}

// ---- implicit-GEMM conv3x3 via MFMA + fused GN partial stats ---------------
// block: ROWS output rows x 64 co, 4 waves. wave = 1 row x (128/NW) px.
// LDS: (ROWS+2) rows x 130 px x 32 ci (padded px slots 0/129 zeroed once).
// Single-buffered, manual coalesced staging (proven best: R3 124MB FETCH).
// ROWS=2 -> 33 KB LDS -> 4 blocks/CU; conv1 grid 1024 = 4 blocks/CU resident.
template<int Ci, int Co, int ROWS, int CPG>
__global__ __launch_bounds__(256, 2) void conv_mfma_k(
    const __hip_bfloat16* __restrict__ xin,  // NHWC bf16 [4][16384][Ci]
    const __hip_bfloat16* __restrict__ wpk,  // [9][Co][Ci] bf16
    const float* __restrict__ bias,
    float* __restrict__ out,                 // NHWC fp32 [4][16384][Co]
    float* __restrict__ partS, float* __restrict__ partSS)
{
  constexpr int NW = 4 / ROWS;         // waves along px
  constexpr int WN = 128 / NW;         // px per wave
  constexpr int NT = WN / 16;
  constexpr int MT = 4;                // 64 co per block
  constexpr int SR = ROWS + 2;
  constexpr int RG = 128 / ROWS;
  constexpr int NG = 64 / CPG;
  __shared__ __align__(16) short bl[SR*130*32];

  const int b  = blockIdx.x / RG;
  const int r0 = (blockIdx.x % RG) * ROWS;
  const int co0 = blockIdx.y * 64;
  const int tid = threadIdx.x;
  const int wave = tid >> 6, lane = tid & 63;
  const int row_w = wave % ROWS;
  const int wn    = wave / ROWS;
  const int y = r0 + row_w;
  const int lr = lane & 15, q = lane >> 4;

  // zero the px-pad slots (px index 0 and 129) once
  if (tid < SR*2*4) {
    int q16 = tid & 3, sp = tid >> 2;
    int r = sp >> 1, side = sp & 1;
    short8 z = {0,0,0,0,0,0,0,0};
    *(short8*)(bl + (r*130 + (side ? 129 : 0))*32 + q16*8) = z;
  }

  f32x4 acc[MT][NT] = {};
  const size_t in_base = (size_t)b * HW * Ci;

  for (int ci0 = 0; ci0 < Ci; ci0 += 32) {
    __syncthreads();
    // stage SR rows x 128 px x 32 ci (4 consecutive threads = 64B line)
    #pragma unroll
    for (int it = 0; it < 2*SR; ++it) {
      int idx = tid + it*256;
      int q16 = idx & 3, px = (idx >> 2) & 127, r = idx >> 9;
      int yy = r0 + r - 1;
      short8 v = {0,0,0,0,0,0,0,0};
      if ((unsigned)yy < 128u)
        v = *(const short8*)(xin + in_base + (size_t)(yy*128 + px)*Ci + ci0 + q16*8);
      *(short8*)(bl + (r*130 + px + 1)*32 + q16*8) = v;
    }
    __syncthreads();
    #pragma unroll
    for (int t = 0; t < 9; ++t) {
      const int dy = t / 3, dx = t % 3;
      short8 af[MT], bf[NT];
      #pragma unroll
      for (int mt = 0; mt < MT; ++mt)
        af[mt] = *(const short8*)(wpk +
            ((size_t)(t*Co + co0 + mt*16 + lr))*Ci + ci0 + q*8);
      #pragma unroll
      for (int nt = 0; nt < NT; ++nt)
        bf[nt] = *(const short8*)(bl + ((row_w + dy)*130 + wn*WN + nt*16 + lr + dx)*32 + q*8);
      #pragma unroll
      for (int mt = 0; mt < MT; ++mt)
        #pragma unroll
        for (int nt = 0; nt < NT; ++nt)
          acc[mt][nt] = __builtin_amdgcn_mfma_f32_16x16x32_bf16(
              af[mt], bf[nt], acc[mt][nt], 0, 0, 0);
    }
  }

  // epilogue: +bias, store, fused GN partial stats
  float sg[NG] = {}, ssg[NG] = {};
  #pragma unroll
  for (int mt = 0; mt < MT; ++mt) {
    const int g = (mt*16) / CPG;
    #pragma unroll
    for (int nt = 0; nt < NT; ++nt) {
      int px = wn*WN + nt*16 + lr;
      int co = co0 + mt*16 + q*4;
      const float4 bv = *(const float4*)(bias + co);
      f32x4 v = acc[mt][nt];
      v[0] += bv.x; v[1] += bv.y; v[2] += bv.z; v[3] += bv.w;
      sg[g]  += v[0] + v[1] + v[2] + v[3];
      ssg[g] += v[0]*v[0] + v[1]*v[1] + v[2]*v[2] + v[3]*v[3];
      *(f32x4*)(out + ((size_t)(b*HW + y*128 + px))*Co + co) = v;
    }
  }
  const int bgbase = b*(Co/CPG) + co0/CPG;
  #pragma unroll
  for (int g = 0; g < NG; ++g) {
    float s = sg[g], ss = ssg[g];
    #pragma unroll
    for (int off = 32; off; off >>= 1) {
      s  += __shfl_xor(s, off);
      ss += __shfl_xor(ss, off);
    }
    if (lane == 0) {
      atomicAdd(&partS[bgbase + g], s);
      atomicAdd(&partSS[bgbase + g], ss);
    }
  }
}

// ---- GN finalize -----------------------------------------------------------
__global__ void gn_final_k(const float* __restrict__ partS,
                           const float* __restrict__ partSS,
                           float* __restrict__ mv, int nbg, float inv_n)
{
  const int i = threadIdx.x;
  if (i < nbg) {
    float s = partS[i], ss = partSS[i];
    float mean = s*inv_n, var = ss*inv_n - mean*mean;
    mv[2*i] = mean; mv[2*i+1] = rsqrtf(var + 1e-5f);
  }
}

// ---- GN apply: normalize+affine+ReLU; emit bf16 (or fp32) NHWC -------------
template<int C, int CPG, bool BF16OUT>
__global__ __launch_bounds__(256) void gn_apply_k(const float* __restrict__ in,
    const float* __restrict__ mv, const float* __restrict__ gw,
    const float* __restrict__ gb, void* __restrict__ outp)
{
  constexpr int C4 = C/4;
  constexpr int G = C/CPG;
  const int i = blockIdx.x*256 + threadIdx.x;
  const int c4 = i & (C4-1);
  const int pxb = i >> __builtin_ctz(C4);
  const int b = pxb >> 14;
  const int c = c4*4;
  const int bg = b*G + c/CPG;
  const float mean = mv[2*bg], inv = mv[2*bg+1];
  float4 v = *((const float4*)in + i);
  const float4 w4 = *(const float4*)(gw + c);
  const float4 b4 = *(const float4*)(gb + c);
  float r0 = fmaxf((v.x-mean)*inv*w4.x + b4.x, 0.f);
  float r1 = fmaxf((v.y-mean)*inv*w4.y + b4.y, 0.f);
  float r2 = fmaxf((v.z-mean)*inv*w4.z + b4.z, 0.f);
  float r3 = fmaxf((v.w-mean)*inv*w4.w + b4.w, 0.f);
  if (BF16OUT) {
    uint2 o;
    o.x = ((unsigned)bfbits(r1) << 16) | bfbits(r0);
    o.y = ((unsigned)bfbits(r3) << 16) | bfbits(r2);
    *(uint2*)((__hip_bfloat16*)outp + (size_t)i*4) = o;
  } else {
    *((float4*)outp + i) = make_float4(r0,r1,r2,r3);
  }
}

// ---- pooling ---------------------------------------------------------------
__global__ __launch_bounds__(256) void pool_counts_k(
    const int* __restrict__ masks, float* __restrict__ counts)
{
  __shared__ int hist[KIDS];
  const int b = blockIdx.x;
  if (threadIdx.x < KIDS) hist[threadIdx.x] = 0;
  __syncthreads();
  for (int p = threadIdx.x; p < HW; p += 256) {
    const int m = masks[b*HW + p];
    if (m > 0) atomicAdd(&hist[m-1], 1);
  }
  __syncthreads();
  if (threadIdx.x < KIDS) counts[b*KIDS + threadIdx.x] = (float)hist[threadIdx.x];
}

__global__ __launch_bounds__(256) void pool_sums_k(const float* __restrict__ h3,
    const int* __restrict__ masks, float* __restrict__ sums)
{
  __shared__ float acc[KIDS*64];
  const int b = blockIdx.x >> 5, chunk = blockIdx.x & 31;
  const int tid = threadIdx.x;
  for (int j = tid; j < KIDS*64; j += 256) acc[j] = 0.f;
  __syncthreads();
  const int ch = tid & 63, pi = tid >> 6;
  const int p0 = chunk*512;
  for (int p = p0 + pi; p < p0 + 512; p += 4) {
    int m = masks[b*HW + p];
    if (m > 0) atomicAdd(&acc[(m-1)*64 + ch], h3[((size_t)(b*HW + p))*64 + ch]);
  }
  __syncthreads();
  for (int j = tid; j < KIDS*64; j += 256) atomicAdd(&sums[b*KIDS*64 + j], acc[j]);
}

// ---- heads: one wave per (b,k) ---------------------------------------------
__global__ __launch_bounds__(64) void heads_k(
    const float* __restrict__ sums, const float* __restrict__ counts,
    const float* __restrict__ wb, const float* __restrict__ bb,
    const float* __restrict__ wc, const float* __restrict__ bc,
    float* __restrict__ out)
{
  const int bk = blockIdx.x;
  const int c = threadIdx.x;
  const float pooled = sums[bk*64 + c] / (counts[bk] + 1e-6f);
  #pragma unroll
  for (int o = 0; o < 7; ++o) {
    float t = pooled * wb[o*64 + c];
    for (int off = 32; off > 0; off >>= 1) t += __shfl_down(t, off);
    if (c == 0) out[bk*7 + o] = t + bb[o];
  }
  float t = pooled * wc[c];
  for (int off = 32; off > 0; off >>= 1) t += __shfl_down(t, off);
  if (c == 0) out[BATCH*KIDS*7 + bk] = 1.f / (1.f + expf(-(t + bc[0])));
}

extern "C" void kernel_launch(void* const* d_in, const int* in_sizes, int n_in,
                              void* d_out, int out_size, void* d_ws, size_t ws_size,
                              hipStream_t stream)
{
  const float* x     = (const float*)d_in[0];
  const int*   masks = (const int*)  d_in[1];
  const float* w1 = (const float*)d_in[2];
  const float* b1 = (const float*)d_in[3];
  const float* g1w= (const float*)d_in[4];
  const float* g1b= (const float*)d_in[5];
  const float* w2 = (const float*)d_in[6];
  const float* b2 = (const float*)d_in[7];
  const float* g2w= (const float*)d_in[8];
  const float* g2b= (const float*)d_in[9];
  const float* w3 = (const float*)d_in[10];
  const float* b3 = (const float*)d_in[11];
  const float* g3w= (const float*)d_in[12];
  const float* g3b= (const float*)d_in[13];
  const float* wb = (const float*)d_in[14];
  const float* bb = (const float*)d_in[15];
  const float* wc = (const float*)d_in[16];
  const float* bc = (const float*)d_in[17];
  float* out = (float*)d_out;

  char* ws = (char*)d_ws;
  __hip_bfloat16* xb  = (__hip_bfloat16*)ws;
  __hip_bfloat16* h1b = (__hip_bfloat16*)ws;
  __hip_bfloat16* h2b = (__hip_bfloat16*)(ws + (size_t)(32<<20));
  float*          h3  = (float*)         (ws + (size_t)(48<<20));
  float* c1 = (float*)(ws + (size_t)(64<<20));
  float* c2 = c1;
  float* c3 = (float*)(ws + (size_t)(96<<20));
  __hip_bfloat16* wp1 = (__hip_bfloat16*)(ws + (size_t)(128<<20));
  __hip_bfloat16* wp2 = wp1 + 9*256*512;
  __hip_bfloat16* wp3 = wp2 + 9*128*256;
  char* tail = (char*)(wp3 + 9*64*128);
  float* mv     = (float*)tail;                 // 64
  float* partS  = mv + 64;                      // 64 (layer offs 0/32/48)
  float* partSS = partS + 64;                   // 64
  float* sums   = partSS + 64;                  // 5120
  float* counts = sums + 5120;                  // 80

  zero_k<<<21, 256, 0, stream>>>(partS, 64 + 64 + 5120);

  x_to_nhwc_k<<<16384, 256, 0, stream>>>(x, xb);
  pack_w_k<256,512><<<4608, 256, 0, stream>>>(w1, wp1);
  pack_w_k<128,256><<<1152, 256, 0, stream>>>(w2, wp2);
  pack_w_k< 64,128><<< 288, 256, 0, stream>>>(w3, wp3);

  // layer 1: 512 -> 256, GN(8 groups, cpg 32). ROWS=2 -> 1024 blocks (4/CU).
  conv_mfma_k<512,256,2,32><<<dim3(256,4), 256, 0, stream>>>(
      xb, wp1, b1, c1, partS, partSS);
  gn_final_k<<<1, 64, 0, stream>>>(partS, partSS, mv, 32, 1.f/(32.f*HW));
  gn_apply_k<256,32,true><<<16384, 256, 0, stream>>>(c1, mv, g1w, g1b, h1b);

  // layer 2: 256 -> 128, GN(4 groups, cpg 32)
  conv_mfma_k<256,128,2,32><<<dim3(256,2), 256, 0, stream>>>(
      h1b, wp2, b2, c2, partS + 32, partSS + 32);
  gn_final_k<<<1, 64, 0, stream>>>(partS + 32, partSS + 32, mv, 16, 1.f/(32.f*HW));
  gn_apply_k<128,32,true><<<8192, 256, 0, stream>>>(c2, mv, g2w, g2b, h2b);

  // layer 3: 128 -> 64, GN(4 groups, cpg 16); fp32 out for pooling
  conv_mfma_k<128,64,1,16><<<dim3(512,1), 256, 0, stream>>>(
      h2b, wp3, b3, c3, partS + 48, partSS + 48);
  gn_final_k<<<1, 64, 0, stream>>>(partS + 48, partSS + 48, mv, 16, 1.f/(16.f*HW));
  gn_apply_k<64,16,false><<<4096, 256, 0, stream>>>(c3, mv, g3w, g3b, h3);

  // pooling + heads
  pool_counts_k<<<BATCH, 256, 0, stream>>>(masks, counts);
  pool_sums_k<<<BATCH*32, 256, 0, stream>>>(h3, masks, sums);
  heads_k<<<BATCH*KIDS, 64, 0, stream>>>(sums, counts, wb, bb, wc, bc, out);
}